// Round 7
// baseline (191.150 us; speedup 1.0000x reference)
//
#include <hip/hip_runtime.h>
#include <math.h>

#define EPS 1e-6f

constexpr int B = 8, C = 3, H = 720, W = 1280;
constexpr int OPL = 5;          // outputs per lane: 256 * 5 == 1280 == W
constexpr int WIN = OPL + 20;   // d in [0,20) -> 25-source shared window per lane
constexpr int WP  = W + 32;     // padded cols (window overrun 1299 < 1312)
// log2(1.414) in double precision
constexpr float K_LOG2 = 0.49978254377554356f;

typedef float v2f __attribute__((ext_vector_type(2)));

// One block per (b, y) row. Atomic-free gather, 5 outputs per lane.
// r4/r6 FAILURE ROOT CAUSE (fixed here): tent weights must be derived from
// tx = fl((float)x' - d) -- the reference quantizes tx on the COARSE f32 grid
// (ulp ~1.2e-4 at x'~1280) before computing wa/wc. Computing u = j - d uses a
// 64x finer grid; the weight ZERO-SETS then disagree at knife-edge sources,
// and at near-hole columns (wsum ~ 0, ~12% of pixels for d~U[0,20)) a single
// flipped source swings the output between im (~1) and 0 -> absmax 0.996.
// So: stage tx in the AoS 4th slot; u = tx - fx0 (exact; bit-matches ref).
// DS optimization kept from r6: one float4 {c0*w, c1*w, c2*w, tx} -> 25
// ds_read_b128 instead of 125 ds_read_b32 (r5 evidence: -25% VALU gave +0%
// duration -> not VALU-bound; DS issue ~725 cyc/wave + 50% occupancy is the
// cost). w recomputed in-gather from d~ = x' - tx (trans pipe; clamped to 20
// so the pad's tx=-1e9 cannot reach exp2f(inf)*0 = NaN).
// LDS atomics measured lane-serialized (r1/r2) -> scatter stays dead.
// Reference's global 1.414^(-dmin) factor cancels in res/mask.
__global__ __launch_bounds__(256) void gather_kernel(const float* __restrict__ im,
                                                     const float* __restrict__ disp,
                                                     float* __restrict__ out) {
    __shared__ __attribute__((aligned(16))) float4 sv[WP];

    const int row = blockIdx.x;  // 0 .. B*H-1
    const int b = row / H;
    const int y = row - b * H;
    const int tid = (int)threadIdx.x;

    const float* __restrict__ dr  = disp + (size_t)row * W;
    const float* __restrict__ im0 = im + ((size_t)(b * C + 0) * H + y) * W;
    const float* __restrict__ im1 = im + ((size_t)(b * C + 1) * H + y) * W;
    const float* __restrict__ im2 = im + ((size_t)(b * C + 2) * H + y) * W;

    // ---- stage premultiplied {im*w, tx} into LDS (coalesced b32 loads) ----
    for (int x = tid; x < WP; x += 256) {
        if (x < W) {
            const float d  = dr[x];
            const float w  = exp2f(K_LOG2 * d);   // 1.414^d
            const float tx = (float)x - d;        // REF'S GRID -- do not refactor
            sv[x] = make_float4(im0[x] * w, im1[x] * w, im2[x] * w, tx);
        } else {
            // pad: tx=-1e9 -> |u-k| huge -> bw = 0; values 0; d~ clamps to 20.
            sv[x] = make_float4(0.f, 0.f, 0.f, -1.0e9f);
        }
    }
    __syncthreads();

    // ---- gather: lane handles outputs [base, base+OPL) ----
    const int base = tid * OPL;
    const float fx0 = (float)base;
    v2f a01[OPL], a23[OPL];                      // {c0,c1} and {c2,wsum}
    #pragma unroll
    for (int k = 0; k < OPL; ++k) {
        a01[k] = (v2f){0.f, 0.f};
        a23[k] = (v2f){0.f, 0.f};
    }

    #pragma unroll 5
    for (int j = 0; j < WIN; ++j) {
        const float4 v = sv[base + j];           // ds_read_b128, conflict-free
        const float tx = v.w;
        const float u  = tx - fx0;               // exact; ref-grid weights
        // d~ == d rounded on the tx grid (Sterbenz-exact subtraction);
        // fminf guards pad (1e9 -> 20) so w~ stays finite; w~/w = 1 +- 2e-5.
        const float dd = fminf((float)(base + j) - tx, 20.0f);
        const float w  = exp2f(K_LOG2 * dd);     // trans pipe, overlaps VALU
        const v2f v01 = {v.x, v.y};
        const v2f v23 = {v.z, w};
        #pragma unroll
        for (int k = 0; k < OPL; ++k) {
            // bit-matches ref's wa (floor(tx)==x) / wc (floor(tx)==x-1)
            const float bw = fmaxf(1.0f - fabsf(u - (float)k), 0.0f);
            a01[k] += v01 * bw;                  // v_pk_fma_f32
            a23[k] += v23 * bw;
        }
    }
    __syncthreads();                             // window reads done: sv reusable

    // ---- normalize, restage planar into sv storage, coalesced store ----
    float* rbuf = (float*)sv;                    // 3*W = 3840 floats <= 5248
    #pragma unroll
    for (int k = 0; k < OPL; ++k) {
        const float inv = __builtin_amdgcn_rcpf(fmaxf(a23[k].y, EPS));
        rbuf[0 * W + base + k] = a01[k].x * inv; // stride-5 b32: 2/bank, free
        rbuf[1 * W + base + k] = a01[k].y * inv;
        rbuf[2 * W + base + k] = a23[k].x * inv;
    }
    __syncthreads();

    float* __restrict__ o0 = out + ((size_t)(b * C + 0) * H + y) * W;
    float* __restrict__ o1 = out + ((size_t)(b * C + 1) * H + y) * W;
    float* __restrict__ o2 = out + ((size_t)(b * C + 2) * H + y) * W;
    for (int x = tid; x < W; x += 256) {
        o0[x] = rbuf[0 * W + x];
        o1[x] = rbuf[1 * W + x];
        o2[x] = rbuf[2 * W + x];
    }
}

extern "C" void kernel_launch(void* const* d_in, const int* in_sizes, int n_in,
                              void* d_out, int out_size, void* d_ws, size_t ws_size,
                              hipStream_t stream) {
    const float* im   = (const float*)d_in[0];
    const float* disp = (const float*)d_in[1];
    float* out = (float*)d_out;
    (void)d_ws; (void)ws_size;

    gather_kernel<<<B * H, 256, 0, stream>>>(im, disp, out);
}